// Round 4
// baseline (489.640 us; speedup 1.0000x reference)
//
#include <hip/hip_runtime.h>

typedef __bf16 bf16_t;
typedef __bf16 bf16x8 __attribute__((ext_vector_type(8)));
typedef __bf16 bf16x4 __attribute__((ext_vector_type(4)));
typedef float f32x4 __attribute__((ext_vector_type(4)));

constexpr int TDIM = 8192;
constexpr int KDIM = 4096;
constexpr int ODIM = 4096;

// Async global->LDS, 16B per lane. LDS dest is wave-uniform base + lane*16 (fixed);
// the per-lane global SOURCE address carries the bank swizzle.
__device__ __forceinline__ void async_ld16(void* lds, const void* g) {
    __builtin_amdgcn_global_load_lds(
        (const __attribute__((address_space(1))) unsigned int*)g,
        (__attribute__((address_space(3))) unsigned int*)lds,
        16, 0, 0);
}

// fp32 -> bf16 for BOTH tensors in one launch. 8 floats/thread:
// two 16B loads -> one 16B store (coalescing sweet spot, G13).
__global__ __launch_bounds__(256) void cvt2_kernel(const float* __restrict__ a, bf16_t* __restrict__ da,
                                                   int nblk_a,
                                                   const float* __restrict__ w, bf16_t* __restrict__ dw) {
    int b = blockIdx.x;
    const float* src;
    bf16_t* dst;
    if (b < nblk_a) { src = a; dst = da; }
    else            { src = w; dst = dw; b -= nblk_a; }
    const size_t base = (size_t)b * 2048 + threadIdx.x * 8;
    const float4 v0 = *(const float4*)(src + base);
    const float4 v1 = *(const float4*)(src + base + 4);
    bf16x8 o;
    o[0] = (bf16_t)v0.x; o[1] = (bf16_t)v0.y; o[2] = (bf16_t)v0.z; o[3] = (bf16_t)v0.w;
    o[4] = (bf16_t)v1.x; o[5] = (bf16_t)v1.y; o[6] = (bf16_t)v1.z; o[7] = (bf16_t)v1.w;
    *(bf16x8*)(dst + base) = o;
}

// ---------------------------------------------------------------------------
// 256x256 8-phase GEMM with READ-AHEAD — the R2-VERIFIED schedule (two
// barriers per phase), with the last iteration peeled so the steady-state
// loop is branch-free. Instruction sequence identical to the verified run.
//
// Phase body: [stage (+vmcnt at P4/P8)] BAR; lgkm(0); MFMA; ra-reads(next); BAR
// RAW: WV6 in the P4/P8 stage window before the pre-MFMA barrier certifies
// block-wide landing of everything through P1 (resp. P5).
// WAR: every ra-read's data is consumed (lgkm(0)) >=1 barrier before the
// stage that overwrites its region.
// ---------------------------------------------------------------------------
constexpr int BM = 256, BN = 256, BK = 64;
constexpr int NKT = KDIM / BK;   // 64 K-tiles
constexpr int NIT = NKT / 2;     // 32 iterations

#define BAR   __builtin_amdgcn_s_barrier()
#define SCB   __builtin_amdgcn_sched_barrier(0)
#define WLG   asm volatile("s_waitcnt lgkmcnt(0)" ::: "memory")
#define WV6   asm volatile("s_waitcnt vmcnt(6)" ::: "memory")
#define WV0   asm volatile("s_waitcnt vmcnt(0)" ::: "memory")
#define PRIO1 __builtin_amdgcn_s_setprio(1)
#define PRIO0 __builtin_amdgcn_s_setprio(0)

// Stage one half-tile (128 rows x 64 k) = 2 global_load_lds per thread.
#define STG_A(c, kt, h) \
    async_ld16(lds_a + (c)*32768 + (h)*16384,        a_srcb + (size_t)((h)*128     )*KDIM + (kt)*64); \
    async_ld16(lds_a + (c)*32768 + (h)*16384 + 8192, a_srcb + (size_t)((h)*128 + 64)*KDIM + (kt)*64)
#define STG_B(c, kt, h) \
    async_ld16(lds_b + (c)*32768 + (h)*16384,        b_srcb + (size_t)((h)*128     )*KDIM + (kt)*64); \
    async_ld16(lds_b + (c)*32768 + (h)*16384 + 8192, b_srcb + (size_t)((h)*128 + 64)*KDIM + (kt)*64)

#define LD_A_LO(c) _Pragma("unroll") for (int m = 0; m < 4; ++m) { \
    af[m][0] = *(const bf16x8*)(a_rd + (c)*32768 + m*2048 + ck0); \
    af[m][1] = *(const bf16x8*)(a_rd + (c)*32768 + m*2048 + ck1); }
#define LD_A_HI(c) _Pragma("unroll") for (int m = 0; m < 4; ++m) { \
    af[m][0] = *(const bf16x8*)(a_rd + (c)*32768 + (m+4)*2048 + ck0); \
    af[m][1] = *(const bf16x8*)(a_rd + (c)*32768 + (m+4)*2048 + ck1); }
#define LD_B01(c) _Pragma("unroll") for (int n = 0; n < 2; ++n) { \
    bfr[n][0] = *(const bf16x8*)(b_rd + (c)*32768 + n*2048 + ck0); \
    bfr[n][1] = *(const bf16x8*)(b_rd + (c)*32768 + n*2048 + ck1); }
#define LD_B23(c) _Pragma("unroll") for (int n = 2; n < 4; ++n) { \
    bfr[n][0] = *(const bf16x8*)(b_rd + (c)*32768 + n*2048 + ck0); \
    bfr[n][1] = *(const bf16x8*)(b_rd + (c)*32768 + n*2048 + ck1); }

#define MFMA16(MB, NB) \
  _Pragma("unroll") for (int m = 0; m < 4; ++m) \
  _Pragma("unroll") for (int n = 0; n < 2; ++n) \
  _Pragma("unroll") for (int k = 0; k < 2; ++k) \
    acc[(MB)+m][(NB)+n] = __builtin_amdgcn_mfma_f32_16x16x32_bf16( \
        af[m][k], bfr[(NB)+n][k], acc[(MB)+m][(NB)+n], 0, 0, 0)

__global__ __launch_bounds__(512, 2) void gemm8_kernel(
    const bf16_t* __restrict__ A, const bf16_t* __restrict__ B,
    const float* __restrict__ scale_x, const float* __restrict__ scale_w,
    const float* __restrict__ gscale, const float* __restrict__ bias,
    float* __restrict__ out)
{
    __shared__ __attribute__((aligned(16))) char smem[131072];

    const int tid = threadIdx.x;
    // T1: bijective XCD swizzle (512 % 8 == 0); bn fast within an XCD.
    const int lin = (blockIdx.x & 7) * 64 + (blockIdx.x >> 3);
    const int row0 = (lin >> 4) * BM;   // 32 M-tiles (t)
    const int col0 = (lin & 15) * BN;   // 16 N-tiles (o)

    // staging map: thread t -> LDS slot (row t>>3, phys chunk t&7) per 64-row line
    const int ld_row = tid >> 3;
    const int ld_ch  = (tid & 7) ^ (ld_row & 7);   // logical chunk to fetch
    const bf16_t* a_srcb = A + (size_t)(row0 + ld_row) * KDIM + ld_ch * 8;
    const bf16_t* b_srcb = B + (size_t)(col0 + ld_row) * KDIM + ld_ch * 8;
    char* lds_a = smem + tid * 16;
    char* lds_b = smem + 65536 + tid * 16;

    // fragment read map
    const int lane = tid & 63;
    const int wid  = tid >> 6;
    const int wm   = wid >> 2;          // 0..1  (128-row slab)
    const int wn   = wid & 3;           // 0..3  (64-col slab)
    const int fr   = lane & 15;
    const int q    = lane >> 4;         // k-quad
    const int swz  = lane & 7;          // == (frag row)&7 for all mt/nt
    const int ck0  = ((q ^ swz)) * 16;        // ks=0 physical chunk byte
    const int ck1  = (((4 | q) ^ swz)) * 16;  // ks=1
    const char* a_rd = smem + (wm * 128 + fr) * 128;
    const char* b_rd = smem + 65536 + (wn * 64 + fr) * 128;

    f32x4 acc[8][4] = {};
    bf16x8 af[4][2], bfr[4][2];

    // Prologue: tile0 -> buf0 (8 loads), tile1 {B0,B1,A0} -> buf1 (6 loads).
    // vmcnt(6): own tile0 landed; BAR certifies block-wide; read-ahead P1.
    STG_B(0, 0, 0); STG_B(0, 0, 1);
    STG_A(0, 0, 0); STG_A(0, 0, 1);
    STG_B(1, 1, 0); STG_B(1, 1, 1);
    STG_A(1, 1, 0);
    WV6; SCB; BAR; SCB;
    LD_A_LO(0); LD_B01(0); SCB;

    // Steady-state: i = 0 .. NIT-2 (pf always true, last always false).
#pragma unroll 1
    for (int i = 0; i < NIT - 1; ++i) {
        const int tp = 2 * i + 2;          // prefetch K-tile pair base
        // ---- P1 : MFMA LOx01(buf0); carry-stage buf1.A1 (tile 2i+1) ----
        STG_A(1, 2 * i + 1, 1);
        BAR; WLG; SCB;
        PRIO1; MFMA16(0, 0); PRIO0; SCB;
        LD_B23(0); SCB; BAR; SCB;
        // ---- P2 : MFMA LOx23(buf0); stage buf0.B0 (tile tp) ----
        STG_B(0, tp, 0);
        BAR; WLG; SCB;
        PRIO1; MFMA16(0, 2); PRIO0; SCB;
        LD_A_HI(0); SCB; BAR; SCB;
        // ---- P3 : MFMA HIx01(buf0); stage buf0.B1 ----
        STG_B(0, tp, 1);
        BAR; WLG; SCB;
        PRIO1; MFMA16(4, 0); PRIO0; SCB; BAR; SCB;
        // ---- P4 : MFMA HIx23(buf0); stage buf0.A0; vmcnt certifies buf1 ----
        STG_A(0, tp, 0);
        WV6; SCB; BAR; SCB;
        PRIO1; MFMA16(4, 2); PRIO0; SCB;
        LD_A_LO(1); LD_B01(1); SCB; BAR; SCB;
        // ---- P5 : MFMA LOx01(buf1); stage buf0.A1 ----
        STG_A(0, tp, 1);
        BAR; WLG; SCB;
        PRIO1; MFMA16(0, 0); PRIO0; SCB;
        LD_B23(1); SCB; BAR; SCB;
        // ---- P6 : MFMA LOx23(buf1); stage buf1.B0 (tile tp+1) ----
        STG_B(1, tp + 1, 0);
        BAR; WLG; SCB;
        PRIO1; MFMA16(0, 2); PRIO0; SCB;
        LD_A_HI(1); SCB; BAR; SCB;
        // ---- P7 : MFMA HIx01(buf1); stage buf1.B1 ----
        STG_B(1, tp + 1, 1);
        BAR; WLG; SCB;
        PRIO1; MFMA16(4, 0); PRIO0; SCB; BAR; SCB;
        // ---- P8 : MFMA HIx23(buf1); stage buf1.A0; vmcnt certifies buf0 ----
        STG_A(1, tp + 1, 0);
        WV6; SCB; BAR; SCB;
        PRIO1; MFMA16(4, 2); PRIO0; SCB;
        LD_A_LO(0); LD_B01(0);
        SCB; BAR; SCB;
    }

    // Final iteration (i = NIT-1): no prefetch stages; drain at P4; no tail reads.
    {
        // ---- P1 ----
        STG_A(1, NKT - 1, 1);
        BAR; WLG; SCB;
        PRIO1; MFMA16(0, 0); PRIO0; SCB;
        LD_B23(0); SCB; BAR; SCB;
        // ---- P2 ----
        BAR; WLG; SCB;
        PRIO1; MFMA16(0, 2); PRIO0; SCB;
        LD_A_HI(0); SCB; BAR; SCB;
        // ---- P3 ----
        BAR; WLG; SCB;
        PRIO1; MFMA16(4, 0); PRIO0; SCB; BAR; SCB;
        // ---- P4 : drain everything (incl. P1 carry) ----
        WV0; SCB; BAR; SCB;
        PRIO1; MFMA16(4, 2); PRIO0; SCB;
        LD_A_LO(1); LD_B01(1); SCB; BAR; SCB;
        // ---- P5 ----
        BAR; WLG; SCB;
        PRIO1; MFMA16(0, 0); PRIO0; SCB;
        LD_B23(1); SCB; BAR; SCB;
        // ---- P6 ----
        BAR; WLG; SCB;
        PRIO1; MFMA16(0, 2); PRIO0; SCB;
        LD_A_HI(1); SCB; BAR; SCB;
        // ---- P7 ----
        BAR; WLG; SCB;
        PRIO1; MFMA16(4, 0); PRIO0; SCB; BAR; SCB;
        // ---- P8 ----
        WV6; SCB; BAR; SCB;
        PRIO1; MFMA16(4, 2); PRIO0; SCB;
        SCB; BAR; SCB;
    }

    // Epilogue: C/D layout col=lane&15, row=(lane>>4)*4+reg [m89/m91-verified]
    const float gs = gscale[0];
    const int trow = row0 + wm * 128 + q * 4;
    const int ocol = col0 + wn * 64 + fr;
#pragma unroll
    for (int nt = 0; nt < 4; ++nt) {
        const int o = ocol + nt * 16;
        const float sws = scale_w[o] * gs;
        const float bv = bias[o];
#pragma unroll
        for (int mt = 0; mt < 8; ++mt) {
#pragma unroll
            for (int ii = 0; ii < 4; ++ii) {
                const int t = trow + mt * 16 + ii;
                out[(size_t)t * ODIM + o] = acc[mt][nt][ii] * (scale_x[t] * sws) + bv;
            }
        }
    }
}

// ---------------------------------------------------------------------------
// Fallback (no workspace): previous verified 128x128 kernel, fp32-load path.
// ---------------------------------------------------------------------------
constexpr int FBM = 128, FBN = 128, FBK = 32;

__global__ __launch_bounds__(256, 4) void gemm_fallback(
    const float* __restrict__ Afp, const float* __restrict__ Bfp,
    const float* __restrict__ scale_x, const float* __restrict__ scale_w,
    const float* __restrict__ gscale, const float* __restrict__ bias,
    float* __restrict__ out) {
    __shared__ bf16_t sA[FBM * FBK];
    __shared__ bf16_t sB[FBN * FBK];

    const int tid = threadIdx.x;
    const int bn = blockIdx.x & 31;
    const int bm = blockIdx.x >> 5;
    const int row0 = bm * FBM;
    const int col0 = bn * FBN;

    const int lane = tid & 63;
    const int wid = tid >> 6;
    const int wm = (wid >> 1) * 64;
    const int wn = (wid & 1) * 64;
    const int fr = lane & 15;
    const int q  = lane >> 4;
    const int s_fr = (fr >> 1) & 3;
    const int kc = ((q ^ s_fr) * 8);

    f32x4 acc[4][4] = {};

    for (int k0 = 0; k0 < KDIM; k0 += FBK) {
        const int r = tid >> 2;
        const int cg2 = (tid & 3) ^ ((tid >> 3) & 3);
#pragma unroll
        for (int h = 0; h < 2; ++h) {
            const int rr = r + h * 64;
            const float4 va0 = *(const float4*)(Afp + (size_t)(row0 + rr) * KDIM + k0 + cg2 * 8);
            const float4 va1 = *(const float4*)(Afp + (size_t)(row0 + rr) * KDIM + k0 + cg2 * 8 + 4);
            const float4 vb0 = *(const float4*)(Bfp + (size_t)(col0 + rr) * KDIM + k0 + cg2 * 8);
            const float4 vb1 = *(const float4*)(Bfp + (size_t)(col0 + rr) * KDIM + k0 + cg2 * 8 + 4);
            bf16x8 pa, pb;
            pa[0] = (bf16_t)va0.x; pa[1] = (bf16_t)va0.y; pa[2] = (bf16_t)va0.z; pa[3] = (bf16_t)va0.w;
            pa[4] = (bf16_t)va1.x; pa[5] = (bf16_t)va1.y; pa[6] = (bf16_t)va1.z; pa[7] = (bf16_t)va1.w;
            pb[0] = (bf16_t)vb0.x; pb[1] = (bf16_t)vb0.y; pb[2] = (bf16_t)vb0.z; pb[3] = (bf16_t)vb0.w;
            pb[4] = (bf16_t)vb1.x; pb[5] = (bf16_t)vb1.y; pb[6] = (bf16_t)vb1.z; pb[7] = (bf16_t)vb1.w;
            *(bf16x8*)&sA[rr * FBK + (tid & 3) * 8] = pa;
            *(bf16x8*)&sB[rr * FBK + (tid & 3) * 8] = pb;
        }
        __syncthreads();

        bf16x8 a8[4], b8[4];
#pragma unroll
        for (int mt = 0; mt < 4; ++mt)
            a8[mt] = *(const bf16x8*)&sA[(wm + mt * 16 + fr) * FBK + kc];
#pragma unroll
        for (int nt = 0; nt < 4; ++nt)
            b8[nt] = *(const bf16x8*)&sB[(wn + nt * 16 + fr) * FBK + kc];
#pragma unroll
        for (int mt = 0; mt < 4; ++mt)
#pragma unroll
            for (int nt = 0; nt < 4; ++nt)
                acc[mt][nt] = __builtin_amdgcn_mfma_f32_16x16x32_bf16(a8[mt], b8[nt], acc[mt][nt], 0, 0, 0);
        __syncthreads();
    }

    const float gs = gscale[0];
    const int rbase = q * 4;
#pragma unroll
    for (int nt = 0; nt < 4; ++nt) {
        const int o = col0 + wn + nt * 16 + fr;
        const float swv = scale_w[o] * gs;
        const float bv = bias[o];
#pragma unroll
        for (int mt = 0; mt < 4; ++mt) {
#pragma unroll
            for (int i = 0; i < 4; ++i) {
                const int t = row0 + wm + mt * 16 + rbase + i;
                out[(size_t)t * ODIM + o] = acc[mt][nt][i] * (scale_x[t] * swv) + bv;
            }
        }
    }
}

extern "C" void kernel_launch(void* const* d_in, const int* in_sizes, int n_in,
                              void* d_out, int out_size, void* d_ws, size_t ws_size,
                              hipStream_t stream) {
    const float* qx   = (const float*)d_in[0];  // (T,K)
    const float* W    = (const float*)d_in[1];  // (O,K)
    const float* sx   = (const float*)d_in[2];  // (T,1)
    const float* sw   = (const float*)d_in[3];  // (O,)
    const float* gs   = (const float*)d_in[4];  // (1,)
    const float* bias = (const float*)d_in[5];  // (O,)
    float* out = (float*)d_out;

    const size_t nA = (size_t)TDIM * KDIM;
    const size_t nW = (size_t)ODIM * KDIM;

    if (ws_size >= (nA + nW) * sizeof(bf16_t)) {
        bf16_t* Abf = (bf16_t*)d_ws;
        bf16_t* Wbf = Abf + nA;
        const int nblk_a = (int)(nA / 2048);
        const int nblk_w = (int)(nW / 2048);
        cvt2_kernel<<<dim3(nblk_a + nblk_w), dim3(256), 0, stream>>>(qx, Abf, nblk_a, W, Wbf);
        gemm8_kernel<<<dim3((TDIM / BM) * (ODIM / BN)), dim3(512), 0, stream>>>(
            Abf, Wbf, sx, sw, gs, bias, out);
    } else {
        gemm_fallback<<<dim3((TDIM / FBM) * (ODIM / FBN)), dim3(256), 0, stream>>>(
            qx, W, sx, sw, gs, bias, out);
    }
}